// Round 5
// baseline (363.624 us; speedup 1.0000x reference)
//
#include <hip/hip_runtime.h>

#define N_NODES 100000
#define N_EDGES 600000
#define DIM     128
#define NGRAPHS 64
#define NPAD    100096   // 782 * 128
#define BCAP    32

typedef short  short8 __attribute__((ext_vector_type(8)));
typedef float  f32x4  __attribute__((ext_vector_type(4)));

__device__ __forceinline__ void atomAddF(float* p, float v) { unsafeAtomicAdd(p, v); }

__device__ __forceinline__ unsigned short f2bf(float f) {
    unsigned int u = __builtin_bit_cast(unsigned int, f);
    u += 0x7fffu + ((u >> 16) & 1u);          // RTN-even
    return (unsigned short)(u >> 16);
}
__device__ __forceinline__ float bflo2f(unsigned int packed) {
    return __builtin_bit_cast(float, packed << 16);
}
__device__ __forceinline__ float bfhi2f(unsigned int packed) {
    return __builtin_bit_cast(float, packed & 0xffff0000u);
}

// ---------------- cast x f32 -> bf16 (pad rows zeroed) + zero cursor/cnt/out ----------------
__global__ void cast_kernel(const float* __restrict__ x, unsigned short* __restrict__ xb,
                            int* __restrict__ cursor, int* __restrict__ cnt,
                            float* __restrict__ outz) {
    int t = blockIdx.x * blockDim.x + threadIdx.x;      // one per 8 elems
    if (t < NPAD) cursor[t] = 0;
    if (t < NGRAPHS) cnt[t] = 0;
    if (t < NGRAPHS * DIM) outz[t] = 0.0f;
    size_t i8 = (size_t)t * 8;
    if (i8 >= (size_t)NPAD * DIM) return;
    uint4 o = make_uint4(0, 0, 0, 0);
    if (i8 < (size_t)N_NODES * DIM) {
        float4 v0 = *reinterpret_cast<const float4*>(x + i8);
        float4 v1 = *reinterpret_cast<const float4*>(x + i8 + 4);
        o.x = (unsigned)f2bf(v0.x) | ((unsigned)f2bf(v0.y) << 16);
        o.y = (unsigned)f2bf(v0.z) | ((unsigned)f2bf(v0.w) << 16);
        o.z = (unsigned)f2bf(v1.x) | ((unsigned)f2bf(v1.y) << 16);
        o.w = (unsigned)f2bf(v1.z) | ((unsigned)f2bf(v1.w) << 16);
    }
    *reinterpret_cast<uint4*>(xb + i8) = o;
}

// ---------------- weight prep: Bt[col][k] bf16 (linear); bias combine ----------------
__global__ void prep_kernel(const float* __restrict__ Ws, const float* __restrict__ Wn,
                            const float* __restrict__ bs, const float* __restrict__ bn,
                            unsigned short* __restrict__ Btg, float* __restrict__ biasg) {
    int t = blockIdx.x * blockDim.x + threadIdx.x;      // 3*128*256 = 98304
    if (t >= 3 * 128 * 256) return;
    int layer = t >> 15;
    int rem   = t & 32767;
    int k     = rem >> 7;          // 0..255
    int col   = rem & 127;         // coalesced over col
    float w = (k < 128) ? Ws[layer * 16384 + k * 128 + col]
                        : Wn[layer * 16384 + (k - 128) * 128 + col];
    Btg[layer * 32768 + col * 256 + k] = f2bf(w);
    if (t < 3 * 128) biasg[t] = bs[t] + bn[t];
}

// ---------------- adjacency build + graph counts (merged) ----------------
__global__ void fillcnt_kernel(const int* __restrict__ src, const int* __restrict__ dst,
                               int* __restrict__ bucket, int* __restrict__ cursor,
                               const int* __restrict__ batch, int* __restrict__ cnt) {
    __shared__ int bins[NGRAPHS];
    if (threadIdx.x < NGRAPHS) bins[threadIdx.x] = 0;
    __syncthreads();
    int t = blockIdx.x * blockDim.x + threadIdx.x;
    if (t < N_EDGES) {
        int d = dst[t];
        int pos = atomicAdd(&cursor[d], 1);
        if (pos < BCAP) bucket[d * BCAP + pos] = src[t];
    }
    if (t < N_NODES) atomicAdd(&bins[batch[t]], 1);
    __syncthreads();
    if (threadIdx.x < NGRAPHS && bins[threadIdx.x] != 0)
        atomicAdd(&cnt[threadIdx.x], bins[threadIdx.x]);
}

// ---------------- gather (bf16): agg[n] = mean_{s in adj(n)} x[s] ----------------
// 16 lanes per node (8 channels each), 16 nodes per 256-thread block.
// Indices prefetched 4-wide -> 4 independent row loads in flight.
__launch_bounds__(256)
__global__ void gather_kernel(const unsigned short* __restrict__ x,
                              const int* __restrict__ bucket,
                              const int* __restrict__ cursor,
                              unsigned short* __restrict__ agg) {
    const int l16  = threadIdx.x & 15;
    const int node = blockIdx.x * 16 + (threadIdx.x >> 4);
    const int k = min(cursor[node], BCAP);
    const int* __restrict__ bl = bucket + (size_t)node * BCAP;
    const size_t co = (size_t)l16 * 8;
    float acc[8];
#pragma unroll
    for (int i = 0; i < 8; ++i) acc[i] = 0.f;

    int j = 0;
    for (; j + 4 <= k; j += 4) {
        int4 s4 = *reinterpret_cast<const int4*>(bl + j);
        uint4 v0 = *reinterpret_cast<const uint4*>(x + (size_t)s4.x * DIM + co);
        uint4 v1 = *reinterpret_cast<const uint4*>(x + (size_t)s4.y * DIM + co);
        uint4 v2 = *reinterpret_cast<const uint4*>(x + (size_t)s4.z * DIM + co);
        uint4 v3 = *reinterpret_cast<const uint4*>(x + (size_t)s4.w * DIM + co);
        acc[0] += bflo2f(v0.x) + bflo2f(v1.x) + bflo2f(v2.x) + bflo2f(v3.x);
        acc[1] += bfhi2f(v0.x) + bfhi2f(v1.x) + bfhi2f(v2.x) + bfhi2f(v3.x);
        acc[2] += bflo2f(v0.y) + bflo2f(v1.y) + bflo2f(v2.y) + bflo2f(v3.y);
        acc[3] += bfhi2f(v0.y) + bfhi2f(v1.y) + bfhi2f(v2.y) + bfhi2f(v3.y);
        acc[4] += bflo2f(v0.z) + bflo2f(v1.z) + bflo2f(v2.z) + bflo2f(v3.z);
        acc[5] += bfhi2f(v0.z) + bfhi2f(v1.z) + bfhi2f(v2.z) + bfhi2f(v3.z);
        acc[6] += bflo2f(v0.w) + bflo2f(v1.w) + bflo2f(v2.w) + bflo2f(v3.w);
        acc[7] += bfhi2f(v0.w) + bfhi2f(v1.w) + bfhi2f(v2.w) + bfhi2f(v3.w);
    }
    for (; j < k; ++j) {
        int s = bl[j];
        uint4 v = *reinterpret_cast<const uint4*>(x + (size_t)s * DIM + co);
        acc[0] += bflo2f(v.x); acc[1] += bfhi2f(v.x);
        acc[2] += bflo2f(v.y); acc[3] += bfhi2f(v.y);
        acc[4] += bflo2f(v.z); acc[5] += bfhi2f(v.z);
        acc[6] += bflo2f(v.w); acc[7] += bfhi2f(v.w);
    }
    const float inv = (k > 0) ? 1.0f / (float)k : 0.0f;
    uint4 o;
    o.x = (unsigned)f2bf(acc[0] * inv) | ((unsigned)f2bf(acc[1] * inv) << 16);
    o.y = (unsigned)f2bf(acc[2] * inv) | ((unsigned)f2bf(acc[3] * inv) << 16);
    o.z = (unsigned)f2bf(acc[4] * inv) | ((unsigned)f2bf(acc[5] * inv) << 16);
    o.w = (unsigned)f2bf(acc[6] * inv) | ((unsigned)f2bf(acc[7] * inv) << 16);
    *reinterpret_cast<uint4*>(agg + (size_t)node * DIM + co) = o;
}

// ---------------- MFMA GEMM, no LDS: AGG = relu([X | AGG] @ Bt^T + bias) ----------------
// 256 threads = 4 waves, 128 rows/block, wave tile 32x128. B read from global (L2).
// Operands SWAPPED in mfma so each lane holds 4 consecutive output cols.
__launch_bounds__(256)
__global__ void gemm_kernel(const unsigned short* __restrict__ X,
                            unsigned short* AGG,
                            const unsigned short* __restrict__ Btg,
                            const float* __restrict__ biasg) {
    const int tid  = threadIdx.x;
    const int wave = tid >> 6;
    const int lane = tid & 63;
    const int l15  = lane & 15;
    const int lk   = lane >> 4;          // 0..3
    const int row_base = blockIdx.x * 128 + wave * 32;

    f32x4 bias4[8];
#pragma unroll
    for (int c = 0; c < 8; ++c)
        bias4[c] = *reinterpret_cast<const f32x4*>(biasg + c * 16 + lk * 4);

    f32x4 acc[2][8];
#pragma unroll
    for (int r = 0; r < 2; ++r)
#pragma unroll
        for (int c = 0; c < 8; ++c) acc[r][c] = (f32x4)0.f;

#pragma unroll 2
    for (int s = 0; s < 8; ++s) {
        const unsigned short* __restrict__ base = (s < 4) ? X : AGG;
        const int kofs = (s & 3) * 32 + lk * 8;
        short8 a0 = *reinterpret_cast<const short8*>(base + (size_t)(row_base + l15) * DIM + kofs);
        short8 a1 = *reinterpret_cast<const short8*>(base + (size_t)(row_base + 16 + l15) * DIM + kofs);
        const int kidx = s * 32 + lk * 8;
#pragma unroll
        for (int c = 0; c < 8; ++c) {
            short8 b = *reinterpret_cast<const short8*>(Btg + (c * 16 + l15) * 256 + kidx);
            // swapped: D[i][j] = C[row_base + j][c*16 + i]; lane l15 = C-row, regs = 4 consecutive cols
            acc[0][c] = __builtin_amdgcn_mfma_f32_16x16x32_bf16(b, a0, acc[0][c], 0, 0, 0);
            acc[1][c] = __builtin_amdgcn_mfma_f32_16x16x32_bf16(b, a1, acc[1][c], 0, 0, 0);
        }
    }

    // epilogue: lane holds C[row_base + r*16 + l15][c*16 + lk*4 + (0..3)]
#pragma unroll
    for (int r = 0; r < 2; ++r) {
        const size_t rowoff = (size_t)(row_base + r * 16 + l15) * DIM;
#pragma unroll
        for (int c = 0; c < 8; ++c) {
            float f0 = fmaxf(acc[r][c][0] + bias4[c][0], 0.f);
            float f1 = fmaxf(acc[r][c][1] + bias4[c][1], 0.f);
            float f2 = fmaxf(acc[r][c][2] + bias4[c][2], 0.f);
            float f3 = fmaxf(acc[r][c][3] + bias4[c][3], 0.f);
            uint2 o;
            o.x = (unsigned)f2bf(f0) | ((unsigned)f2bf(f1) << 16);
            o.y = (unsigned)f2bf(f2) | ((unsigned)f2bf(f3) << 16);
            *reinterpret_cast<uint2*>(AGG + rowoff + c * 16 + lk * 4) = o;
        }
    }
}

// ---------------- pooling (bf16 in, f32 out) ----------------
__global__ void pool_kernel(const unsigned short* __restrict__ x,
                            const int* __restrict__ batch,
                            float* __restrict__ out) {
    int q = threadIdx.x;
    int node0 = blockIdx.x * 32;
    float local = 0.0f;
    int prev = batch[node0];
    for (int nd = node0; nd < node0 + 32; ++nd) {
        int b = batch[nd];
        if (b != prev) {
            atomAddF(&out[prev * DIM + q], local);
            local = 0.0f;
            prev = b;
        }
        local += bflo2f((unsigned int)x[(size_t)nd * DIM + q]);
    }
    atomAddF(&out[prev * DIM + q], local);
}

__global__ void div_kernel(float* __restrict__ out, const int* __restrict__ cnt) {
    int t = blockIdx.x * blockDim.x + threadIdx.x;
    if (t < NGRAPHS * DIM) out[t] *= 1.0f / (float)max(cnt[t >> 7], 1);
}

// ---------------- launch ----------------
extern "C" void kernel_launch(void* const* d_in, const int* in_sizes, int n_in,
                              void* d_out, int out_size, void* d_ws, size_t ws_size,
                              hipStream_t stream) {
    const float* x        = (const float*)d_in[0];
    const int*   ei       = (const int*)d_in[1];
    const int*   src      = ei;
    const int*   dst      = ei + N_EDGES;
    const int*   batch    = (const int*)d_in[2];
    const float* Ws_self  = (const float*)d_in[3];
    const float* bs_self  = (const float*)d_in[4];
    const float* Ws_neigh = (const float*)d_in[5];
    const float* bs_neigh = (const float*)d_in[6];
    float* out = (float*)d_out;

    const size_t NB = (size_t)NPAD * DIM;
    unsigned short* xb     = (unsigned short*)d_ws;     // NB
    unsigned short* b0     = xb + NB;                   // NB
    unsigned short* b1     = b0 + NB;                   // NB
    unsigned short* Btg    = b1 + NB;                   // 3*32768
    float*          biasg  = (float*)(Btg + 3 * 32768); // 384
    int*            bucket = (int*)(biasg + 384);       // NPAD*BCAP
    int*            cursor = bucket + (size_t)NPAD * BCAP;
    int*            cnt    = cursor + NPAD;             // NGRAPHS

    cast_kernel<<<(int)((NB / 8 + 255) / 256), 256, 0, stream>>>(x, xb, cursor, cnt, out);
    prep_kernel<<<384, 256, 0, stream>>>(Ws_self, Ws_neigh, bs_self, bs_neigh, Btg, biasg);
    fillcnt_kernel<<<(N_EDGES + 255) / 256, 256, 0, stream>>>(src, dst, bucket, cursor, batch, cnt);

    const int ga_grid = NPAD / 16;    // 6256
    const int gm_grid = NPAD / 128;   // 782

    // layer 0
    gather_kernel<<<ga_grid, 256, 0, stream>>>(xb, bucket, cursor, b1);
    gemm_kernel<<<gm_grid, 256, 0, stream>>>(xb, b1, Btg, biasg);
    // layer 1
    gather_kernel<<<ga_grid, 256, 0, stream>>>(b1, bucket, cursor, b0);
    gemm_kernel<<<gm_grid, 256, 0, stream>>>(b1, b0, Btg + 32768, biasg + 128);
    // layer 2
    gather_kernel<<<ga_grid, 256, 0, stream>>>(b0, bucket, cursor, b1);
    gemm_kernel<<<gm_grid, 256, 0, stream>>>(b0, b1, Btg + 65536, biasg + 256);

    // pooling
    pool_kernel<<<N_NODES / 32, DIM, 0, stream>>>(b1, batch, out);
    div_kernel<<<(NGRAPHS * DIM + 255) / 256, 256, 0, stream>>>(out, cnt);
}

// Round 6
// 292.144 us; speedup vs baseline: 1.2447x; 1.2447x over previous
//
#include <hip/hip_runtime.h>

#define N_NODES 100000
#define N_EDGES 600000
#define DIM     128
#define NGRAPHS 64
#define NPAD    100096   // 782 * 128
#define BCAP    32

typedef short  short8 __attribute__((ext_vector_type(8)));
typedef float  f32x4  __attribute__((ext_vector_type(4)));

__device__ __forceinline__ void atomAddF(float* p, float v) { unsafeAtomicAdd(p, v); }

__device__ __forceinline__ unsigned short f2bf(float f) {
    unsigned int u = __builtin_bit_cast(unsigned int, f);
    u += 0x7fffu + ((u >> 16) & 1u);          // RTN-even
    return (unsigned short)(u >> 16);
}
__device__ __forceinline__ float bflo2f(unsigned int packed) {
    return __builtin_bit_cast(float, packed << 16);
}
__device__ __forceinline__ float bfhi2f(unsigned int packed) {
    return __builtin_bit_cast(float, packed & 0xffff0000u);
}

// ---------------- cast x f32 -> bf16 (pad rows zeroed) + zero cursor/cnt/out ----------------
__global__ void cast_kernel(const float* __restrict__ x, unsigned short* __restrict__ xb,
                            int* __restrict__ cursor, int* __restrict__ cnt,
                            float* __restrict__ outz) {
    int t = blockIdx.x * blockDim.x + threadIdx.x;      // one per 8 elems
    if (t < NPAD) cursor[t] = 0;
    if (t < NGRAPHS) cnt[t] = 0;
    if (t < NGRAPHS * DIM) outz[t] = 0.0f;
    size_t i8 = (size_t)t * 8;
    if (i8 >= (size_t)NPAD * DIM) return;
    uint4 o = make_uint4(0, 0, 0, 0);
    if (i8 < (size_t)N_NODES * DIM) {
        float4 v0 = *reinterpret_cast<const float4*>(x + i8);
        float4 v1 = *reinterpret_cast<const float4*>(x + i8 + 4);
        o.x = (unsigned)f2bf(v0.x) | ((unsigned)f2bf(v0.y) << 16);
        o.y = (unsigned)f2bf(v0.z) | ((unsigned)f2bf(v0.w) << 16);
        o.z = (unsigned)f2bf(v1.x) | ((unsigned)f2bf(v1.y) << 16);
        o.w = (unsigned)f2bf(v1.z) | ((unsigned)f2bf(v1.w) << 16);
    }
    *reinterpret_cast<uint4*>(xb + i8) = o;
}

// ---------------- weight prep: Bt[col][k] bf16, XOR-swizzled for LDS; bias combine ----------------
__global__ void prep_kernel(const float* __restrict__ Ws, const float* __restrict__ Wn,
                            const float* __restrict__ bs, const float* __restrict__ bn,
                            unsigned short* __restrict__ Btg, float* __restrict__ biasg) {
    int t = blockIdx.x * blockDim.x + threadIdx.x;      // 3*128*256 = 98304
    if (t >= 3 * 128 * 256) return;
    int layer = t >> 15;
    int rem   = t & 32767;
    int k     = rem >> 7;          // 0..255
    int col   = rem & 127;         // coalesced over col
    float w = (k < 128) ? Ws[layer * 16384 + k * 128 + col]
                        : Wn[layer * 16384 + (k - 128) * 128 + col];
    Btg[layer * 32768 + col * 256 + (k ^ ((col & 7) << 3))] = f2bf(w);
    if (t < 3 * 128) biasg[t] = bs[t] + bn[t];
}

// ---------------- adjacency build + graph counts (merged) ----------------
__global__ void fillcnt_kernel(const int* __restrict__ src, const int* __restrict__ dst,
                               int* __restrict__ bucket, int* __restrict__ cursor,
                               const int* __restrict__ batch, int* __restrict__ cnt) {
    __shared__ int bins[NGRAPHS];
    if (threadIdx.x < NGRAPHS) bins[threadIdx.x] = 0;
    __syncthreads();
    int t = blockIdx.x * blockDim.x + threadIdx.x;
    if (t < N_EDGES) {
        int d = dst[t];
        int pos = atomicAdd(&cursor[d], 1);
        if (pos < BCAP) bucket[d * BCAP + pos] = src[t];
    }
    if (t < N_NODES) atomicAdd(&bins[batch[t]], 1);
    __syncthreads();
    if (threadIdx.x < NGRAPHS && bins[threadIdx.x] != 0)
        atomicAdd(&cnt[threadIdx.x], bins[threadIdx.x]);
}

// ---------------- gather (bf16): agg[n] = mean_{s in adj(n)} x[s] ----------------
// 16 lanes per node (8 channels each), 16 nodes per 256-thread block.
// Indices prefetched 4-wide -> 4 independent row loads in flight.
__launch_bounds__(256)
__global__ void gather_kernel(const unsigned short* __restrict__ x,
                              const int* __restrict__ bucket,
                              const int* __restrict__ cursor,
                              unsigned short* __restrict__ agg) {
    const int l16  = threadIdx.x & 15;
    const int node = blockIdx.x * 16 + (threadIdx.x >> 4);
    const int k = min(cursor[node], BCAP);
    const int* __restrict__ bl = bucket + (size_t)node * BCAP;
    const size_t co = (size_t)l16 * 8;
    float acc[8];
#pragma unroll
    for (int i = 0; i < 8; ++i) acc[i] = 0.f;

    int j = 0;
    for (; j + 4 <= k; j += 4) {
        int4 s4 = *reinterpret_cast<const int4*>(bl + j);
        uint4 v0 = *reinterpret_cast<const uint4*>(x + (size_t)s4.x * DIM + co);
        uint4 v1 = *reinterpret_cast<const uint4*>(x + (size_t)s4.y * DIM + co);
        uint4 v2 = *reinterpret_cast<const uint4*>(x + (size_t)s4.z * DIM + co);
        uint4 v3 = *reinterpret_cast<const uint4*>(x + (size_t)s4.w * DIM + co);
        acc[0] += bflo2f(v0.x) + bflo2f(v1.x) + bflo2f(v2.x) + bflo2f(v3.x);
        acc[1] += bfhi2f(v0.x) + bfhi2f(v1.x) + bfhi2f(v2.x) + bfhi2f(v3.x);
        acc[2] += bflo2f(v0.y) + bflo2f(v1.y) + bflo2f(v2.y) + bflo2f(v3.y);
        acc[3] += bfhi2f(v0.y) + bfhi2f(v1.y) + bfhi2f(v2.y) + bfhi2f(v3.y);
        acc[4] += bflo2f(v0.z) + bflo2f(v1.z) + bflo2f(v2.z) + bflo2f(v3.z);
        acc[5] += bfhi2f(v0.z) + bfhi2f(v1.z) + bfhi2f(v2.z) + bfhi2f(v3.z);
        acc[6] += bflo2f(v0.w) + bflo2f(v1.w) + bflo2f(v2.w) + bflo2f(v3.w);
        acc[7] += bfhi2f(v0.w) + bfhi2f(v1.w) + bfhi2f(v2.w) + bfhi2f(v3.w);
    }
    for (; j < k; ++j) {
        int s = bl[j];
        uint4 v = *reinterpret_cast<const uint4*>(x + (size_t)s * DIM + co);
        acc[0] += bflo2f(v.x); acc[1] += bfhi2f(v.x);
        acc[2] += bflo2f(v.y); acc[3] += bfhi2f(v.y);
        acc[4] += bflo2f(v.z); acc[5] += bfhi2f(v.z);
        acc[6] += bflo2f(v.w); acc[7] += bfhi2f(v.w);
    }
    const float inv = (k > 0) ? 1.0f / (float)k : 0.0f;
    uint4 o;
    o.x = (unsigned)f2bf(acc[0] * inv) | ((unsigned)f2bf(acc[1] * inv) << 16);
    o.y = (unsigned)f2bf(acc[2] * inv) | ((unsigned)f2bf(acc[3] * inv) << 16);
    o.z = (unsigned)f2bf(acc[4] * inv) | ((unsigned)f2bf(acc[5] * inv) << 16);
    o.w = (unsigned)f2bf(acc[6] * inv) | ((unsigned)f2bf(acc[7] * inv) << 16);
    *reinterpret_cast<uint4*>(agg + (size_t)node * DIM + co) = o;
}

// ---------------- MFMA GEMM: AGG = relu([X | AGG] @ Bt^T + bias) ----------------
// 512 threads = 8 waves, 256 rows/block, wave tile 32x128.
// B^T (pre-swizzled) staged ONCE into LDS; K-loop has no barriers.
// Operands swapped in mfma so each lane holds 4 consecutive output cols.
__launch_bounds__(512)
__global__ void gemm_kernel(const unsigned short* __restrict__ X,
                            unsigned short* AGG,
                            const unsigned short* __restrict__ Btg,
                            const float* __restrict__ biasg) {
    __shared__ unsigned short Blds[128 * 256];   // 64 KB

    const int tid  = threadIdx.x;
    // stage B^T: linear 64 KB copy (pre-swizzled in global)
#pragma unroll
    for (int i = 0; i < 8; ++i) {
        int idx8 = (i * 512 + tid) * 8;
        *reinterpret_cast<uint4*>(Blds + idx8) =
            *reinterpret_cast<const uint4*>(Btg + idx8);
    }
    __syncthreads();

    const int wave = tid >> 6;
    const int lane = tid & 63;
    const int l15  = lane & 15;
    const int lk   = lane >> 4;          // 0..3
    const int row_base = blockIdx.x * 256 + wave * 32;
    const int swz = (l15 & 7) << 3;

    f32x4 bias4[8];
#pragma unroll
    for (int c = 0; c < 8; ++c)
        bias4[c] = *reinterpret_cast<const f32x4*>(biasg + c * 16 + lk * 4);

    f32x4 acc[2][8];
#pragma unroll
    for (int r = 0; r < 2; ++r)
#pragma unroll
        for (int c = 0; c < 8; ++c) acc[r][c] = (f32x4)0.f;

#pragma unroll 2
    for (int s = 0; s < 8; ++s) {
        const unsigned short* __restrict__ base = (s < 4) ? X : AGG;
        const int kofs = (s & 3) * 32 + lk * 8;
        short8 a0 = *reinterpret_cast<const short8*>(base + (size_t)(row_base + l15) * DIM + kofs);
        short8 a1 = *reinterpret_cast<const short8*>(base + (size_t)(row_base + 16 + l15) * DIM + kofs);
        const int kidx = s * 32 + lk * 8;
#pragma unroll
        for (int c = 0; c < 8; ++c) {
            short8 b = *reinterpret_cast<const short8*>(Blds + (c * 16 + l15) * 256 + (kidx ^ swz));
            // swapped: lane l15 indexes activation row, regs = 4 consecutive output cols
            acc[0][c] = __builtin_amdgcn_mfma_f32_16x16x32_bf16(b, a0, acc[0][c], 0, 0, 0);
            acc[1][c] = __builtin_amdgcn_mfma_f32_16x16x32_bf16(b, a1, acc[1][c], 0, 0, 0);
        }
    }

    // epilogue: lane holds C[row_base + r*16 + l15][c*16 + lk*4 + (0..3)]
#pragma unroll
    for (int r = 0; r < 2; ++r) {
        const size_t rowoff = (size_t)(row_base + r * 16 + l15) * DIM;
#pragma unroll
        for (int c = 0; c < 8; ++c) {
            float f0 = fmaxf(acc[r][c][0] + bias4[c][0], 0.f);
            float f1 = fmaxf(acc[r][c][1] + bias4[c][1], 0.f);
            float f2 = fmaxf(acc[r][c][2] + bias4[c][2], 0.f);
            float f3 = fmaxf(acc[r][c][3] + bias4[c][3], 0.f);
            uint2 o;
            o.x = (unsigned)f2bf(f0) | ((unsigned)f2bf(f1) << 16);
            o.y = (unsigned)f2bf(f2) | ((unsigned)f2bf(f3) << 16);
            *reinterpret_cast<uint2*>(AGG + rowoff + c * 16 + lk * 4) = o;
        }
    }
}

// ---------------- pooling (bf16 in, f32 out) ----------------
__global__ void pool_kernel(const unsigned short* __restrict__ x,
                            const int* __restrict__ batch,
                            float* __restrict__ out) {
    int q = threadIdx.x;
    int node0 = blockIdx.x * 32;
    float local = 0.0f;
    int prev = batch[node0];
    for (int nd = node0; nd < node0 + 32; ++nd) {
        int b = batch[nd];
        if (b != prev) {
            atomAddF(&out[prev * DIM + q], local);
            local = 0.0f;
            prev = b;
        }
        local += bflo2f((unsigned int)x[(size_t)nd * DIM + q]);
    }
    atomAddF(&out[prev * DIM + q], local);
}

__global__ void div_kernel(float* __restrict__ out, const int* __restrict__ cnt) {
    int t = blockIdx.x * blockDim.x + threadIdx.x;
    if (t < NGRAPHS * DIM) out[t] *= 1.0f / (float)max(cnt[t >> 7], 1);
}

// ---------------- launch ----------------
extern "C" void kernel_launch(void* const* d_in, const int* in_sizes, int n_in,
                              void* d_out, int out_size, void* d_ws, size_t ws_size,
                              hipStream_t stream) {
    const float* x        = (const float*)d_in[0];
    const int*   ei       = (const int*)d_in[1];
    const int*   src      = ei;
    const int*   dst      = ei + N_EDGES;
    const int*   batch    = (const int*)d_in[2];
    const float* Ws_self  = (const float*)d_in[3];
    const float* bs_self  = (const float*)d_in[4];
    const float* Ws_neigh = (const float*)d_in[5];
    const float* bs_neigh = (const float*)d_in[6];
    float* out = (float*)d_out;

    const size_t NB = (size_t)NPAD * DIM;
    unsigned short* xb     = (unsigned short*)d_ws;     // NB
    unsigned short* b0     = xb + NB;                   // NB
    unsigned short* b1     = b0 + NB;                   // NB
    unsigned short* Btg    = b1 + NB;                   // 3*32768
    float*          biasg  = (float*)(Btg + 3 * 32768); // 384
    int*            bucket = (int*)(biasg + 384);       // NPAD*BCAP
    int*            cursor = bucket + (size_t)NPAD * BCAP;
    int*            cnt    = cursor + NPAD;             // NGRAPHS

    cast_kernel<<<(int)((NB / 8 + 255) / 256), 256, 0, stream>>>(x, xb, cursor, cnt, out);
    prep_kernel<<<384, 256, 0, stream>>>(Ws_self, Ws_neigh, bs_self, bs_neigh, Btg, biasg);
    fillcnt_kernel<<<(N_EDGES + 255) / 256, 256, 0, stream>>>(src, dst, bucket, cursor, batch, cnt);

    const int ga_grid = NPAD / 16;    // 6256
    const int gm_grid = NPAD / 256;   // 391

    // layer 0
    gather_kernel<<<ga_grid, 256, 0, stream>>>(xb, bucket, cursor, b1);
    gemm_kernel<<<gm_grid, 512, 0, stream>>>(xb, b1, Btg, biasg);
    // layer 1
    gather_kernel<<<ga_grid, 256, 0, stream>>>(b1, bucket, cursor, b0);
    gemm_kernel<<<gm_grid, 512, 0, stream>>>(b1, b0, Btg + 32768, biasg + 128);
    // layer 2
    gather_kernel<<<ga_grid, 256, 0, stream>>>(b0, bucket, cursor, b1);
    gemm_kernel<<<gm_grid, 512, 0, stream>>>(b0, b1, Btg + 65536, biasg + 256);

    // pooling
    pool_kernel<<<N_NODES / 32, DIM, 0, stream>>>(b1, batch, out);
    div_kernel<<<(NGRAPHS * DIM + 255) / 256, 256, 0, stream>>>(out, cnt);
}